// Round 3
// baseline (120.992 us; speedup 1.0000x reference)
//
#include <hip/hip_runtime.h>
#include <math.h>

// Soft silhouette renderer — R21 = R20 + per-tile face BINNING.
// verts: (4, 778, 3) f32   faces: (1538, 3) i32   out: (4, 320, 320) f32
//
// Verified-exact math core (R4, absmax 0.0):
//   area2 = fma(dx1, dy2, -round(dy1*dx2)) — matches the reference
//   evaluator's contraction; degenerate faces (sgn=0 -> 1/8 veil, i1==i2
//   sliver -> sigma=1/2 ridge) fall out of the generic edge code.
//
// R20 post-mortem: 81.7us (best). Payload compaction netted only ~1us —
// the j-loop chain was NOT dominant. Cost model of silhouette (~38us):
//   staging sweep: 6400 blocks x 1538 faces x 48B = 472MB L2 (~14us)
//                  + ~5us classification VALU  — all redundant work;
//   j-loop: ~220 band faces/tile -> ~716K wave-iters x ~80cy ~ 20us.
// R21 moves classification into a face-parallel BIN kernel (runs once,
// ~2.5M lane-tests ~ 2us) so silhouette reads only its own tile's
// compacted index list (~220 x 52B ~ 11KB vs 74KB) and does zero
// classification math. Cover counts are applied up-front, so saturated
// interior tiles die at the first alive-vote without touching the list.
//
// Binning correctness: the set of tiles where a face can be band/cover
// ({m_hi > -T_CUT}) is the intersection of 3 inflated half-planes
//   c_i(p) + T_CUT + r_i > 0   (|grad c_i| <= 100)
// = an inflated triangle. Its corners come from homogeneous cross
// products of the inflated lines; |w| < 1e-3 (near-parallel / degenerate,
// incl. the sgn=0 veil faces where all lines are 0=0) => full-image
// fallback. Corners get +0.5 edge-value safety (0.8px) and +-1 tile slop,
// clamped to the image. Per-tile classification inside the bbox is
// BIT-IDENTICAL to R20's staging test, so the verified cull budget
// carries over. Band-list order is atomic-nondeterministic: product
// reorder stays within the ~1e-4 rounding allowance.
//
// Error budget vs 2e-2 tolerance (measured 0.00390625 = one bf16 ulp =
// harness quantization floor since R5): cull skip <= 1538*e^-12 = 9.4e-3
// worst-case; branchless factor ~1e-7/face; saturation cut 2.3e-6;
// product rounding ~1e-4 (incl. reorder).
//
// ws: gE0/1/2 (307KB) + bandCnt/coverCnt (51KB) + list 6400x1600 ints
// (41MB) << 256MB ws.

#define IMG_S 320
#define N_TILES 40         // IMG_S / TILE
#define N_FACES 1538
#define N_VERTS 778
#define N_BATCH 4
#define FP 1600            // padded face stride in ws
#define TILE 8
#define MAXB 384           // LDS band chunk (LDS 19.5KB -> 8 blocks/CU)
#define LIST_STRIDE 1600   // >= N_FACES, per-tile list capacity
#define NWAVE 4
#define INV_SIGMA 100.0f
#define T_CUT 12.0f
#define ACC_CUT_P 2.2603294e-6f    // e^-13, product-domain saturation
#define LOG2_1EM6 -19.9315686f     // log2(1e-6)
#define N_BINS (N_BATCH * N_TILES * N_TILES)   // 6400

__global__ __launch_bounds__(256)
void prep_faces(const float* __restrict__ verts,
                const int* __restrict__ faces,
                float4* __restrict__ gE0,
                float4* __restrict__ gE1,
                float4* __restrict__ gE2,
                int* __restrict__ cnts)   // bandCnt ++ coverCnt, 2*N_BINS ints
{
    // zero bin counters first (grid covers 7168 threads, 12800 ints)
    const int g = (blockIdx.z * gridDim.x + blockIdx.x) * 256 + threadIdx.x;
    const int nthr = gridDim.x * gridDim.z * 256;
    for (int i = g; i < 2 * N_BINS; i += nthr) cnts[i] = 0;

    const int f = blockIdx.x * 256 + threadIdx.x;
    const int b = blockIdx.z;
    if (f >= N_FACES) return;

    const float* vb = verts + (size_t)b * N_VERTS * 3;
    const int i0 = faces[f * 3 + 0];
    const int i1 = faces[f * 3 + 1];
    const int i2 = faces[f * 3 + 2];
    const float x0 = vb[i0 * 3 + 0], y0 = -vb[i0 * 3 + 1];
    const float x1 = vb[i1 * 3 + 0], y1 = -vb[i1 * 3 + 1];
    const float x2 = vb[i2 * 3 + 0], y2 = -vb[i2 * 3 + 1];

    // VERIFIED-EXACT (R4): fma-contracted area2 — do not change.
    const float dx1 = x1 - x0, dy1 = y1 - y0;
    const float dx2 = x2 - x0, dy2 = y2 - y0;
    const float area2 = __builtin_fmaf(dx1, dy2, -__fmul_rn(dy1, dx2));
    const float sgn = (area2 > 0.0f) ? 1.0f : ((area2 < 0.0f) ? -1.0f : 0.0f);

    const size_t o = (size_t)b * FP + f;
    {   // edge v0 -> v1
        const float ex = x1 - x0, ey = y1 - y0;
        const float s = sgn * INV_SIGMA / (sqrtf(ex * ex + ey * ey) + 1e-8f);
        gE0[o] = make_float4(-s * ey, s * ex, s * (ey * x0 - ex * y0), 0.0f);
    }
    {   // edge v1 -> v2
        const float ex = x2 - x1, ey = y2 - y1;
        const float s = sgn * INV_SIGMA / (sqrtf(ex * ex + ey * ey) + 1e-8f);
        gE1[o] = make_float4(-s * ey, s * ex, s * (ey * x1 - ex * y1), 0.0f);
    }
    {   // edge v2 -> v0
        const float ex = x0 - x2, ey = y0 - y2;
        const float s = sgn * INV_SIGMA / (sqrtf(ex * ex + ey * ey) + 1e-8f);
        gE2[o] = make_float4(-s * ey, s * ex, s * (ey * x2 - ex * y2), 0.0f);
    }
}

// One wave per face: compute conservative tile bbox, classify each tile in
// it with the EXACT R20 staging test, append band faces / count cover.
__global__ __launch_bounds__(256)
void bin_faces(const float4* __restrict__ gE0,
               const float4* __restrict__ gE1,
               const float4* __restrict__ gE2,
               int* __restrict__ bandCnt,
               int* __restrict__ coverCnt,
               int* __restrict__ list)
{
    const int t    = threadIdx.x;
    const int wave = t >> 6;
    const int lane = t & 63;
    const int f    = blockIdx.x * 4 + wave;
    const int b    = blockIdx.z;
    if (f >= N_FACES) return;   // wave-uniform

    const size_t o = (size_t)b * FP + f;
    const float4 e0 = gE0[o];
    const float4 e1 = gE1[o];
    const float4 e2 = gE2[o];

    const float pw = 2.0f / IMG_S;
    const float rr = 3.5f * pw;
    const float r0 = rr * (fabsf(e0.x) + fabsf(e0.y));
    const float r1 = rr * (fabsf(e1.x) + fabsf(e1.y));
    const float r2 = rr * (fabsf(e2.x) + fabsf(e2.y));

    // inflated lines l_i = (A, B, C + T_CUT + r_i + SAFE)
    const float C0 = e0.z + T_CUT + r0 + 0.5f;
    const float C1 = e1.z + T_CUT + r1 + 0.5f;
    const float C2 = e2.z + T_CUT + r2 + 0.5f;

    float xmn = 1e30f, xmx = -1e30f, ymn = 1e30f, ymx = -1e30f;
    bool ok = true;
    {   // corner l0 x l1
        const float w = e0.x * e1.y - e0.y * e1.x;
        if (fabsf(w) < 1e-3f) ok = false;
        else {
            const float iw = 1.0f / w;
            const float x = (e0.y * C1 - C0 * e1.y) * iw;
            const float y = (C0 * e1.x - e0.x * C1) * iw;
            xmn = fminf(xmn, x); xmx = fmaxf(xmx, x);
            ymn = fminf(ymn, y); ymx = fmaxf(ymx, y);
        }
    }
    {   // corner l1 x l2
        const float w = e1.x * e2.y - e1.y * e2.x;
        if (fabsf(w) < 1e-3f) ok = false;
        else {
            const float iw = 1.0f / w;
            const float x = (e1.y * C2 - C1 * e2.y) * iw;
            const float y = (C1 * e2.x - e1.x * C2) * iw;
            xmn = fminf(xmn, x); xmx = fmaxf(xmx, x);
            ymn = fminf(ymn, y); ymx = fmaxf(ymx, y);
        }
    }
    {   // corner l2 x l0
        const float w = e2.x * e0.y - e2.y * e0.x;
        if (fabsf(w) < 1e-3f) ok = false;
        else {
            const float iw = 1.0f / w;
            const float x = (e2.y * C0 - C2 * e0.y) * iw;
            const float y = (C2 * e0.x - e2.x * C0) * iw;
            xmn = fminf(xmn, x); xmx = fmaxf(xmx, x);
            ymn = fminf(ymn, y); ymx = fmaxf(ymx, y);
        }
    }
    if (!ok || !(xmn <= xmx) || !(ymn <= ymx)) {   // degenerate -> full image
        xmn = -1.0f; xmx = 1.0f; ymn = -1.0f; ymx = 1.0f;
    }
    xmn = fmaxf(xmn, -1.0f); xmx = fminf(xmx, 1.0f);
    ymn = fmaxf(ymn, -1.0f); ymx = fminf(ymx, 1.0f);

    // tile center x of tx: (tx*8+4)*pw - 1  ->  tx = (((x+1)/pw)-4)/8
    const int tx0 = max(0,  (int)floorf(((xmn + 1.0f) * 160.0f - 4.0f) * 0.125f) - 1);
    const int tx1 = min(N_TILES - 1, (int)ceilf(((xmx + 1.0f) * 160.0f - 4.0f) * 0.125f) + 1);
    const int ty0 = max(0,  (int)floorf(((ymn + 1.0f) * 160.0f - 4.0f) * 0.125f) - 1);
    const int ty1 = min(N_TILES - 1, (int)ceilf(((ymx + 1.0f) * 160.0f - 4.0f) * 0.125f) + 1);
    const int nx = tx1 - tx0 + 1;
    const int ny = ty1 - ty0 + 1;
    if (nx <= 0 || ny <= 0) return;
    const int ntile = nx * ny;

    for (int k = lane; k < ntile; k += 64) {
        const int tx = tx0 + k % nx;
        const int ty = ty0 + k / nx;
        const float cxx = (tx * TILE + 4) * pw - 1.0f;
        const float cyy = (ty * TILE + 4) * pw - 1.0f;
        // EXACT same classification as R20 staging — do not change.
        const float c0 = fmaf(e0.x, cxx, fmaf(e0.y, cyy, e0.z));
        const float c1 = fmaf(e1.x, cxx, fmaf(e1.y, cyy, e1.z));
        const float c2 = fmaf(e2.x, cxx, fmaf(e2.y, cyy, e2.z));
        const float m_hi = fminf(c0 + r0, fminf(c1 + r1, c2 + r2));
        const float m_lo = fminf(c0 - r0, fminf(c1 - r1, c2 - r2));
        const int tid = (b * N_TILES + ty) * N_TILES + tx;
        if (m_lo > T_CUT) {
            atomicAdd(&coverCnt[tid], 1);
        } else if (m_hi > -T_CUT) {
            const int s = atomicAdd(&bandCnt[tid], 1);
            list[(size_t)tid * LIST_STRIDE + s] = f;
        }
    }
}

__global__ __launch_bounds__(256)
void silhouette_ws(const float4* __restrict__ gE0,
                   const float4* __restrict__ gE1,
                   const float4* __restrict__ gE2,
                   const int* __restrict__ bandCnt,
                   const int* __restrict__ coverCnt,
                   const int* __restrict__ list,
                   float* __restrict__ out)
{
    __shared__ float4 sE0[MAXB];   // staged band-face edge payloads
    __shared__ float4 sE1[MAXB];
    __shared__ float4 sE2[MAXB];
    __shared__ float sAcc[256];
    __shared__ int sAlive;

    const int t    = threadIdx.x;
    const int wave = t >> 6;
    const int p    = t & 63;          // pixel id within 8x8 tile
    const int plx  = p & 7;
    const int ply  = p >> 3;
    const int b    = blockIdx.z;
    const int gx   = blockIdx.x * TILE + plx;
    const int gy   = blockIdx.y * TILE + ply;

    const float w  = 2.0f / IMG_S;
    const float px = (gx + 0.5f) * w - 1.0f;
    const float py = (gy + 0.5f) * w - 1.0f;

    const float4* gb0 = gE0 + (size_t)b * FP;   // per-batch base
    const float4* gb1 = gE1 + (size_t)b * FP;
    const float4* gb2 = gE2 + (size_t)b * FP;

    const int tid = (b * N_TILES + blockIdx.y) * N_TILES + blockIdx.x;
    const int n   = bandCnt[tid];
    const int cov = coverCnt[tid];
    const int* myList = list + (size_t)tid * LIST_STRIDE;

    // cover fold up-front: wave 0 carries (1e-6)^cov (0 for cov >= 7)
    float acc = (wave == 0) ? exp2f((float)cov * LOG2_1EM6) : 1.0f;

    for (int base = 0; base < n; base += MAXB) {
        const int nn = min(MAXB, n - base);

        sAcc[t] = acc;
        if (t == 0) sAlive = 0;
        __syncthreads();   // B1: resets + partials visible
        const float tot = sAcc[p] * sAcc[p + 64] * sAcc[p + 128] * sAcc[p + 192];
        const bool alive = (tot > ACC_CUT_P);
        if (alive) sAlive = 1;               // benign same-value race
        __syncthreads();   // B2: vote final — break BEFORE staging
                           // (also fences prev chunk's sE reads from this
                           //  chunk's sE writes)
        if (sAlive == 0) break;   // uniform: every pixel saturated

        // stage this chunk's payloads: coalesced index read + L2 gather
        for (int k = t; k < nn; k += 256) {
            const int idx = myList[base + k];
            sE0[k] = gb0[idx];
            sE1[k] = gb1[idx];
            sE2[k] = gb2[idx];
        }
        __syncthreads();   // B3: staging complete

        bool live = alive && (acc > ACC_CUT_P);
        int j = wave;
        while (j < nn) {
            if (__ballot(live) == 0ull) break;   // whole wave saturated
            const int j1 = j + NWAVE;
            const int j1c = (j1 < nn) ? j1 : j;
            // issue both iterations' LDS broadcasts before any compute
            const float4 A0 = sE0[j],   A1 = sE1[j],   A2 = sE2[j];
            const float4 B0 = sE0[j1c], B1 = sE1[j1c], B2 = sE2[j1c];
            {   // iteration 0 — branchless band body
                const float xa = fmaf(A0.x, px, fmaf(A0.y, py, A0.z));
                const float xb = fmaf(A1.x, px, fmaf(A1.y, py, A1.z));
                const float xc = fmaf(A2.x, px, fmaf(A2.y, py, A2.z));
                const float m = fminf(xa, fminf(xb, xc));
                if (live && m > -T_CUT) {
                    const float da = 1.0f + __expf(-xa);
                    const float db = 1.0f + __expf(-xb);
                    const float dc = 1.0f + __expf(-xc);
                    const float f = fmaxf(
                        1.0f - __builtin_amdgcn_rcpf(da * db * dc), 1e-6f);
                    acc *= f;
                    live = (acc > ACC_CUT_P);
                }
            }
            if (j1 < nn) {   // iteration 1
                const float xa = fmaf(B0.x, px, fmaf(B0.y, py, B0.z));
                const float xb = fmaf(B1.x, px, fmaf(B1.y, py, B1.z));
                const float xc = fmaf(B2.x, px, fmaf(B2.y, py, B2.z));
                const float m = fminf(xa, fminf(xb, xc));
                if (live && m > -T_CUT) {
                    const float da = 1.0f + __expf(-xa);
                    const float db = 1.0f + __expf(-xb);
                    const float dc = 1.0f + __expf(-xc);
                    const float f = fmaxf(
                        1.0f - __builtin_amdgcn_rcpf(da * db * dc), 1e-6f);
                    acc *= f;
                    live = (acc > ACC_CUT_P);
                }
            }
            j += 2 * NWAVE;
        }
        // no B4: next chunk's sE writes happen after its B2, which every
        // wave passes only after finishing this j-loop.
    }

    // final reduction + output (loop exits are block-uniform)
    sAcc[t] = acc;
    __syncthreads();
    if (t < 64) {
        const float tot = sAcc[p] * sAcc[p + 64] * sAcc[p + 128] * sAcc[p + 192];
        out[(size_t)b * (IMG_S * IMG_S) + (size_t)gy * IMG_S + gx] = 1.0f - tot;
    }
}

extern "C" void kernel_launch(void* const* d_in, const int* in_sizes, int n_in,
                              void* d_out, int out_size, void* d_ws, size_t ws_size,
                              hipStream_t stream) {
    const float* verts = (const float*)d_in[0];
    const int* faces = (const int*)d_in[1];
    float* out = (float*)d_out;

    // ws layout:
    //   gE0/gE1/gE2 : 3 x 4*1600 float4            = 307,200 B
    //   bandCnt     : 6400 ints                    =  25,600 B
    //   coverCnt    : 6400 ints                    =  25,600 B
    //   list        : 6400 * 1600 ints             = ~41 MB
    float4* gE0 = (float4*)d_ws;
    float4* gE1 = gE0 + (size_t)N_BATCH * FP;
    float4* gE2 = gE1 + (size_t)N_BATCH * FP;
    int* bandCnt  = (int*)(gE2 + (size_t)N_BATCH * FP);
    int* coverCnt = bandCnt + N_BINS;
    int* list     = coverCnt + N_BINS;

    dim3 pgrid((N_FACES + 255) / 256, 1, N_BATCH);
    prep_faces<<<pgrid, 256, 0, stream>>>(verts, faces, gE0, gE1, gE2, bandCnt);

    dim3 bgrid((N_FACES + 3) / 4, 1, N_BATCH);
    bin_faces<<<bgrid, 256, 0, stream>>>(gE0, gE1, gE2, bandCnt, coverCnt, list);

    dim3 grid(IMG_S / TILE, IMG_S / TILE, N_BATCH);
    silhouette_ws<<<grid, 256, 0, stream>>>(gE0, gE1, gE2, bandCnt, coverCnt,
                                            list, out);
}

// Round 4
// 85.949 us; speedup vs baseline: 1.4077x; 1.4077x over previous
//
#include <hip/hip_runtime.h>
#include <math.h>

// Soft silhouette renderer — R22 = R20 + per-face tile-BBOX culling
// (binning inverted: per-face bbox written coalesced in prep, per-tile
// candidate compaction done in LDS — no scattered global writes).
// verts: (4, 778, 3) f32   faces: (1538, 3) i32   out: (4, 320, 320) f32
//
// Verified-exact math core (R4, absmax 0.0):
//   area2 = fma(dx1, dy2, -round(dy1*dx2)) — matches the reference
//   evaluator's contraction; degenerate faces (sgn=0 -> 1/8 veil, i1==i2
//   sliver -> sigma=1/2 ridge) fall out of the generic edge code.
//
// R21 post-mortem: per-tile face lists regressed to 121us. bin_faces was
// 49us on its own: WRITE_SIZE 46MB @ 990GB/s (12% peak) — each wave's 64
// lanes appended 4B ints into 64 DIFFERENT tiles' list regions (one dirty
// cache line per 4B payload, write-allocate) + 2.5M global atomics. The
// cull itself worked (121-49=72 ~= R20 minus predicted staging savings).
//
// R22 keeps the cull but inverts the structure so every global write is
// coalesced:
//  * prep_faces additionally computes the face's conservative tile bbox
//    (R21's inflated-halfplane corner math, verified conservative on this
//    data by R21's passing run; degenerate/near-parallel -> full image)
//    and writes ONE packed int per face (tx0|tx1<<8|ty0<<16|ty1<<24).
//  * silhouette stage 1: sweep the 1538 packed bboxes (7 coalesced 4B
//    passes, L1-resident 6KB), ballot-compact hits into a ushort LDS
//    candidate list (~300/tile typical, capacity 1538 = worst case).
//  * silhouette stage 2: R20's BIT-IDENTICAL classify (m_hi/m_lo vs tile
//    center) + payload compaction, but only over candidates (~2 passes
//    of 256 vs 7 over all faces); payload gather ~15KB vs 74KB per block.
//  * j-loop, alive-votes, cover fold, live gate: unchanged from R20.
// LDS: sE 3*256*16B = 12.3KB + sCand 3.1KB + sAcc 1KB ~= 16.5KB -> 8
// blocks/CU (32-wave cap). No extra kernel launch vs R20.
//
// Error budget vs 2e-2 tolerance (measured 0.00390625 = one bf16 ulp =
// harness quantization floor since R5): cull skip <= 1538*e^-12 = 9.4e-3
// worst-case; branchless factor ~1e-7/face; saturation cut 2.3e-6;
// product rounding ~1e-4 (incl. compaction reorder). Bbox filter is a
// strict superset of {m_hi > -T_CUT} tiles, so classified results are
// identical to R20's.

#define IMG_S 320
#define N_TILES 40         // IMG_S / TILE
#define N_FACES 1538
#define N_VERTS 778
#define N_BATCH 4
#define FP 1600            // padded face stride in ws
#define TILE 8
#define MAXB 256           // LDS band chunk == candidate chunk size
#define MAXCAND 1544       // candidate list capacity (>= N_FACES, even)
#define NWAVE 4
#define INV_SIGMA 100.0f
#define T_CUT 12.0f
#define ACC_CUT_P 2.2603294e-6f    // e^-13, product-domain saturation
#define LOG2_1EM6 -19.9315686f     // log2(1e-6)

__global__ __launch_bounds__(256)
void prep_faces(const float* __restrict__ verts,
                const int* __restrict__ faces,
                float4* __restrict__ gE0,
                float4* __restrict__ gE1,
                float4* __restrict__ gE2,
                unsigned int* __restrict__ gBB)
{
    const int f = blockIdx.x * 256 + threadIdx.x;
    const int b = blockIdx.z;
    if (f >= N_FACES) return;

    const float* vb = verts + (size_t)b * N_VERTS * 3;
    const int i0 = faces[f * 3 + 0];
    const int i1 = faces[f * 3 + 1];
    const int i2 = faces[f * 3 + 2];
    const float x0 = vb[i0 * 3 + 0], y0 = -vb[i0 * 3 + 1];
    const float x1 = vb[i1 * 3 + 0], y1 = -vb[i1 * 3 + 1];
    const float x2 = vb[i2 * 3 + 0], y2 = -vb[i2 * 3 + 1];

    // VERIFIED-EXACT (R4): fma-contracted area2 — do not change.
    const float dx1 = x1 - x0, dy1 = y1 - y0;
    const float dx2 = x2 - x0, dy2 = y2 - y0;
    const float area2 = __builtin_fmaf(dx1, dy2, -__fmul_rn(dy1, dx2));
    const float sgn = (area2 > 0.0f) ? 1.0f : ((area2 < 0.0f) ? -1.0f : 0.0f);

    const size_t o = (size_t)b * FP + f;
    float4 e0, e1, e2;
    {   // edge v0 -> v1
        const float ex = x1 - x0, ey = y1 - y0;
        const float s = sgn * INV_SIGMA / (sqrtf(ex * ex + ey * ey) + 1e-8f);
        e0 = make_float4(-s * ey, s * ex, s * (ey * x0 - ex * y0), 0.0f);
    }
    {   // edge v1 -> v2
        const float ex = x2 - x1, ey = y2 - y1;
        const float s = sgn * INV_SIGMA / (sqrtf(ex * ex + ey * ey) + 1e-8f);
        e1 = make_float4(-s * ey, s * ex, s * (ey * x1 - ex * y1), 0.0f);
    }
    {   // edge v2 -> v0
        const float ex = x0 - x2, ey = y0 - y2;
        const float s = sgn * INV_SIGMA / (sqrtf(ex * ex + ey * ey) + 1e-8f);
        e2 = make_float4(-s * ey, s * ex, s * (ey * x2 - ex * y2), 0.0f);
    }
    gE0[o] = e0;
    gE1[o] = e1;
    gE2[o] = e2;

    // ---- conservative tile bbox (R21's verified corner math) ----
    const float pw = 2.0f / IMG_S;
    const float rr = 3.5f * pw;
    const float r0 = rr * (fabsf(e0.x) + fabsf(e0.y));
    const float r1 = rr * (fabsf(e1.x) + fabsf(e1.y));
    const float r2 = rr * (fabsf(e2.x) + fabsf(e2.y));
    const float C0 = e0.z + T_CUT + r0 + 0.5f;
    const float C1 = e1.z + T_CUT + r1 + 0.5f;
    const float C2 = e2.z + T_CUT + r2 + 0.5f;

    float xmn = 1e30f, xmx = -1e30f, ymn = 1e30f, ymx = -1e30f;
    bool ok = true;
    {   // corner l0 x l1
        const float ww = e0.x * e1.y - e0.y * e1.x;
        if (fabsf(ww) < 1e-3f) ok = false;
        else {
            const float iw = 1.0f / ww;
            const float x = (e0.y * C1 - C0 * e1.y) * iw;
            const float y = (C0 * e1.x - e0.x * C1) * iw;
            xmn = fminf(xmn, x); xmx = fmaxf(xmx, x);
            ymn = fminf(ymn, y); ymx = fmaxf(ymx, y);
        }
    }
    {   // corner l1 x l2
        const float ww = e1.x * e2.y - e1.y * e2.x;
        if (fabsf(ww) < 1e-3f) ok = false;
        else {
            const float iw = 1.0f / ww;
            const float x = (e1.y * C2 - C1 * e2.y) * iw;
            const float y = (C1 * e2.x - e1.x * C2) * iw;
            xmn = fminf(xmn, x); xmx = fmaxf(xmx, x);
            ymn = fminf(ymn, y); ymx = fmaxf(ymx, y);
        }
    }
    {   // corner l2 x l0
        const float ww = e2.x * e0.y - e2.y * e0.x;
        if (fabsf(ww) < 1e-3f) ok = false;
        else {
            const float iw = 1.0f / ww;
            const float x = (e2.y * C0 - C2 * e0.y) * iw;
            const float y = (C2 * e0.x - e2.x * C0) * iw;
            xmn = fminf(xmn, x); xmx = fmaxf(xmx, x);
            ymn = fminf(ymn, y); ymx = fmaxf(ymx, y);
        }
    }
    if (!ok || !(xmn <= xmx) || !(ymn <= ymx)) {   // degenerate -> full image
        xmn = -1.0f; xmx = 1.0f; ymn = -1.0f; ymx = 1.0f;
    }
    xmn = fmaxf(xmn, -1.0f); xmx = fminf(xmx, 1.0f);
    ymn = fmaxf(ymn, -1.0f); ymx = fminf(ymx, 1.0f);

    // tile center of tx: (tx*8+4)*pw - 1  ->  tx = (((x+1)*160)-4)/8
    const int tx0 = max(0,  (int)floorf(((xmn + 1.0f) * 160.0f - 4.0f) * 0.125f) - 1);
    const int tx1 = min(N_TILES - 1, (int)ceilf(((xmx + 1.0f) * 160.0f - 4.0f) * 0.125f) + 1);
    const int ty0 = max(0,  (int)floorf(((ymn + 1.0f) * 160.0f - 4.0f) * 0.125f) - 1);
    const int ty1 = min(N_TILES - 1, (int)ceilf(((ymx + 1.0f) * 160.0f - 4.0f) * 0.125f) + 1);

    gBB[o] = (unsigned)tx0 | ((unsigned)max(tx1, tx0) << 8) |
             ((unsigned)ty0 << 16) | ((unsigned)max(ty1, ty0) << 24);
}

__global__ __launch_bounds__(256)
void silhouette_ws(const float4* __restrict__ gE0,
                   const float4* __restrict__ gE1,
                   const float4* __restrict__ gE2,
                   const unsigned int* __restrict__ gBB,
                   float* __restrict__ out)
{
    __shared__ float4 sE0[MAXB];   // compacted band-face edge payloads
    __shared__ float4 sE1[MAXB];
    __shared__ float4 sE2[MAXB];
    __shared__ unsigned short sCand[MAXCAND];   // bbox-hit face ids
    __shared__ float sAcc[256];
    __shared__ int sNC;
    __shared__ int sCount;
    __shared__ int sAlive;
    __shared__ int sCover;

    const int t    = threadIdx.x;
    const int wave = t >> 6;
    const int lane = t & 63;
    const int p    = t & 63;          // pixel id within 8x8 tile
    const int plx  = p & 7;
    const int ply  = p >> 3;
    const int b    = blockIdx.z;
    const int tx   = blockIdx.x;
    const int ty   = blockIdx.y;
    const int gx   = tx * TILE + plx;
    const int gy   = ty * TILE + ply;

    const float w  = 2.0f / IMG_S;
    const float px = (gx + 0.5f) * w - 1.0f;
    const float py = (gy + 0.5f) * w - 1.0f;
    const float cx = (tx * TILE + 4) * w - 1.0f;
    const float cy = (ty * TILE + 4) * w - 1.0f;
    const float rr = 3.5f * w;

    const float4* gb0 = gE0 + (size_t)b * FP;   // per-batch base
    const float4* gb1 = gE1 + (size_t)b * FP;
    const float4* gb2 = gE2 + (size_t)b * FP;
    const unsigned int* bbb = gBB + (size_t)b * FP;

    // ---- stage 1: bbox sweep -> candidate compaction (once) ----
    if (t == 0) sNC = 0;
    __syncthreads();
    for (int fb = 0; fb < N_FACES; fb += 256) {
        const int f = fb + t;
        bool hit = false;
        if (f < N_FACES) {
            const unsigned bb = bbb[f];
            hit = (tx >= (int)(bb & 255u))         && (tx <= (int)((bb >> 8) & 255u)) &&
                  (ty >= (int)((bb >> 16) & 255u)) && (ty <= (int)(bb >> 24));
        }
        const unsigned long long mh = __ballot(hit);
        int wb = 0;
        if (lane == 0) {
            const int nw = __popcll(mh);
            if (nw) wb = atomicAdd(&sNC, nw);
        }
        wb = __shfl(wb, 0);
        if (hit) sCand[wb + __popcll(mh & ((1ull << lane) - 1ull))] =
                     (unsigned short)f;
    }
    __syncthreads();   // S1: candidate list final
    const int nCand = sNC;

    float acc = 1.0f;   // product of (1-prob) over this wave's face subset
                        // (wave 0 also carries the cover factors)

    for (int base = 0; base < nCand; base += MAXB) {
        const int nn2 = min(MAXB, nCand - base);

        sAcc[t] = acc;
        if (t == 0) { sCount = 0; sAlive = 0; sCover = 0; }
        __syncthreads();   // B1: resets + partials visible
        const float tot = sAcc[p] * sAcc[p + 64] * sAcc[p + 128] * sAcc[p + 192];
        const bool alive = (tot > ACC_CUT_P);
        if (alive) sAlive = 1;               // benign same-value race
        __syncthreads();   // B2: vote final — break BEFORE staging
                           // (also fences prev chunk's sE reads from this
                           //  chunk's sE writes)
        if (sAlive == 0) break;   // uniform: every pixel saturated

        // ---- stage 2: classify candidates, compact band PAYLOADS ----
        {
            const int k = base + t;
            const bool vald = (k < nCand);
            const int fc = sCand[vald ? k : base];
            const float4 e0 = gb0[fc];       // L2-resident gather
            const float4 e1 = gb1[fc];
            const float4 e2 = gb2[fc];
            // EXACT same classification as R20 staging — do not change.
            const float c0 = fmaf(e0.x, cx, fmaf(e0.y, cy, e0.z));
            const float c1 = fmaf(e1.x, cx, fmaf(e1.y, cy, e1.z));
            const float c2 = fmaf(e2.x, cx, fmaf(e2.y, cy, e2.z));
            const float r0 = rr * (fabsf(e0.x) + fabsf(e0.y));
            const float r1 = rr * (fabsf(e1.x) + fabsf(e1.y));
            const float r2 = rr * (fabsf(e2.x) + fabsf(e2.y));
            const float m_hi = fminf(c0 + r0, fminf(c1 + r1, c2 + r2));
            const float m_lo = fminf(c0 - r0, fminf(c1 - r1, c2 - r2));
            const bool isCov  = vald && (m_lo > T_CUT);
            const bool isBand = vald && !isCov && (m_hi > -T_CUT);

            const unsigned long long mb = __ballot(isBand);
            int wbase = 0;
            if (lane == 0) {
                const int nw = __popcll(mb);
                if (nw) wbase = atomicAdd(&sCount, nw);
            }
            wbase = __shfl(wbase, 0);
            if (isBand) {
                const int pos = wbase + __popcll(mb & ((1ull << lane) - 1ull));
                sE0[pos] = e0;               // payload compaction
                sE1[pos] = e1;
                sE2[pos] = e2;
            }
            const unsigned long long mc = __ballot(isCov);
            if (lane == 0) {
                const int ncv = __popcll(mc);
                if (ncv) atomicAdd(&sCover, ncv);
            }
            (void)nn2;
        }
        __syncthreads();   // B3: compaction + cover count final

        const float coverF = exp2f((float)sCover * LOG2_1EM6);
        bool live = alive && (acc * coverF > ACC_CUT_P);
        if (wave == 0) acc *= coverF;

        const int n = sCount;
        int j = wave;
        while (j < n) {
            if (__ballot(live) == 0ull) break;   // whole wave saturated
            const int j1 = j + NWAVE;
            const int j1c = (j1 < n) ? j1 : j;
            // issue both iterations' LDS broadcasts before any compute
            const float4 A0 = sE0[j],   A1 = sE1[j],   A2 = sE2[j];
            const float4 B0 = sE0[j1c], B1 = sE1[j1c], B2 = sE2[j1c];
            {   // iteration 0 — branchless band body
                const float xa = fmaf(A0.x, px, fmaf(A0.y, py, A0.z));
                const float xb = fmaf(A1.x, px, fmaf(A1.y, py, A1.z));
                const float xc = fmaf(A2.x, px, fmaf(A2.y, py, A2.z));
                const float m = fminf(xa, fminf(xb, xc));
                if (live && m > -T_CUT) {
                    const float da = 1.0f + __expf(-xa);
                    const float db = 1.0f + __expf(-xb);
                    const float dc = 1.0f + __expf(-xc);
                    const float f = fmaxf(
                        1.0f - __builtin_amdgcn_rcpf(da * db * dc), 1e-6f);
                    acc *= f;
                    live = (acc > ACC_CUT_P);
                }
            }
            if (j1 < n) {   // iteration 1
                const float xa = fmaf(B0.x, px, fmaf(B0.y, py, B0.z));
                const float xb = fmaf(B1.x, px, fmaf(B1.y, py, B1.z));
                const float xc = fmaf(B2.x, px, fmaf(B2.y, py, B2.z));
                const float m = fminf(xa, fminf(xb, xc));
                if (live && m > -T_CUT) {
                    const float da = 1.0f + __expf(-xa);
                    const float db = 1.0f + __expf(-xb);
                    const float dc = 1.0f + __expf(-xc);
                    const float f = fmaxf(
                        1.0f - __builtin_amdgcn_rcpf(da * db * dc), 1e-6f);
                    acc *= f;
                    live = (acc > ACC_CUT_P);
                }
            }
            j += 2 * NWAVE;
        }
        // no B4: next chunk's sE writes happen after its B2, which every
        // wave passes only after finishing this j-loop.
    }

    // final reduction + output (loop exits are block-uniform)
    sAcc[t] = acc;
    __syncthreads();
    if (t < 64) {
        const float tot = sAcc[p] * sAcc[p + 64] * sAcc[p + 128] * sAcc[p + 192];
        out[(size_t)b * (IMG_S * IMG_S) + (size_t)gy * IMG_S + gx] = 1.0f - tot;
    }
}

extern "C" void kernel_launch(void* const* d_in, const int* in_sizes, int n_in,
                              void* d_out, int out_size, void* d_ws, size_t ws_size,
                              hipStream_t stream) {
    const float* verts = (const float*)d_in[0];
    const int* faces = (const int*)d_in[1];
    float* out = (float*)d_out;

    // ws layout:
    //   gE0/gE1/gE2 : 3 x 4*1600 float4 = 307,200 B
    //   gBB         : 4*1600 uint       =  25,600 B
    float4* gE0 = (float4*)d_ws;
    float4* gE1 = gE0 + (size_t)N_BATCH * FP;
    float4* gE2 = gE1 + (size_t)N_BATCH * FP;
    unsigned int* gBB = (unsigned int*)(gE2 + (size_t)N_BATCH * FP);

    dim3 pgrid((N_FACES + 255) / 256, 1, N_BATCH);
    prep_faces<<<pgrid, 256, 0, stream>>>(verts, faces, gE0, gE1, gE2, gBB);

    dim3 grid(IMG_S / TILE, IMG_S / TILE, N_BATCH);
    silhouette_ws<<<grid, 256, 0, stream>>>(gE0, gE1, gE2, gBB, out);
}